// Round 4
// baseline (1115.037 us; speedup 1.0000x reference)
//
#include <hip/hip_runtime.h>
#include <hip/hip_bf16.h>
#include <hip/hip_cooperative_groups.h>

namespace cg = cooperative_groups;

typedef __attribute__((ext_vector_type(8))) short short8;
typedef __attribute__((ext_vector_type(4))) float floatx4;

__device__ __forceinline__ ushort f2bf(float x) {
    __hip_bfloat16 h = __float2bfloat16(x);
    return __builtin_bit_cast(ushort, h);
}
__device__ __forceinline__ float bf2f(ushort u) {
    __hip_bfloat16 h = __builtin_bit_cast(__hip_bfloat16, u);
    return __bfloat162float(h);
}

// fast tanh: 1 - 2/(e^{2z}+1); v_exp + v_rcp, ~1e-6 abs err
__device__ __forceinline__ float fast_tanh(float z) {
    float e = __expf(2.0f * z);
    return 1.0f - 2.0f * __builtin_amdgcn_rcpf(e + 1.0f);
}

// async global -> LDS, 16 bytes per lane. LDS dest is wave-uniform base + lane*16;
// per-lane GLOBAL source is arbitrary (exploited for the XOR bank swizzle).
__device__ __forceinline__ void gload_lds16(const ushort* g, ushort* l) {
    __builtin_amdgcn_global_load_lds(
        (const __attribute__((address_space(1))) unsigned int*)(const void*)g,
        (__attribute__((address_space(3))) unsigned int*)(void*)l,
        16, 0, 0);
}

// ---------------------------------------------------------------------------
// One GEMM phase: persistent tile loop over 128(M)x256(N) tiles, 8 waves/block.
// A [M][1024] bf16, BT [NOUT][1024] bf16. Epilogue by MODE:
//   1: out_bf = bf2f(A[row][col]) + 0.1*tanh(acc+bias)   (euler step)
//   2: out_bf = relu(acc+bias)
//   3: out_f32 = tanh(acc+bias)
// Tile id: xcd band = id&7 (grid and strides are multiples of 8, so a block's
// tiles stay in its XCD's A-band); N-tiles innermost for L2 A-reuse.
// ---------------------------------------------------------------------------
template <int MODE, int NOUT, int NX>
__device__ __forceinline__ void gemm_phase(
    const ushort* __restrict__ A, const ushort* __restrict__ BT,
    const float* __restrict__ bias,
    ushort* __restrict__ outB, float* __restrict__ outF,
    int nTiles, ushort* As, ushort* Bs) {
    constexpr int K = 1024;
    const int tid = threadIdx.x;
    const int wave = tid >> 6, lane = tid & 63;
    const int waveM = wave >> 2;      // 0..1  (64-row band)
    const int waveN = wave & 3;       // 0..3  (64-col band)

    // XOR bank swizzle constants: physical 16B slot c holds logical
    // (row r=c>>2, quad q=(c&3)^((r>>1)&3)).
    const int ca = wave * 64 + lane;
    const int ra = ca >> 2;
    const int qa = (ca & 3) ^ ((ra >> 1) & 3);
    ushort* asD  = As + (size_t)(wave * 64) * 8;
    ushort* bsD0 = Bs + (size_t)(wave * 64) * 8;
    ushort* bsD1 = Bs + (size_t)(wave * 64 + 512) * 8;

    const int mrow = lane & 15;
    const int g = lane >> 4;
    const int pq = g ^ ((mrow >> 1) & 3);
    const int kqOff = pq * 8;

    for (int id = blockIdx.x; id < nTiles; id += gridDim.x) {
        const int inner = id >> 3;
        const int nTile = inner % NX;
        const int mTile = (id & 7) * 32 + inner / NX;
        const int mBase = mTile * 128;
        const int nBase = nTile * 256;

        const ushort* agA = A + (size_t)(mBase + ra) * K + qa * 8;
        const ushort* bg0 = BT + (size_t)(nBase + ra) * K + qa * 8;
        const ushort* bg1 = BT + (size_t)(nBase + ra + 128) * K + qa * 8;

        floatx4 acc[4][4];
        #pragma unroll
        for (int i = 0; i < 4; i++)
            #pragma unroll
            for (int j = 0; j < 4; j++) acc[i][j] = (floatx4)(0.f);

        for (int k0 = 0; k0 < K; k0 += 32) {
            gload_lds16(agA + k0, asD);
            gload_lds16(bg0 + k0, bsD0);
            gload_lds16(bg1 + k0, bsD1);
            __syncthreads();

            short8 af[4], bfr[4];
            #pragma unroll
            for (int t = 0; t < 4; t++) {
                af[t]  = *(const short8*)(As + (waveM * 64 + t * 16 + mrow) * 32 + kqOff);
                bfr[t] = *(const short8*)(Bs + (waveN * 64 + t * 16 + mrow) * 32 + kqOff);
            }
            #pragma unroll
            for (int mt = 0; mt < 4; mt++)
                #pragma unroll
                for (int nt = 0; nt < 4; nt++)
                    acc[mt][nt] = __builtin_amdgcn_mfma_f32_16x16x32_bf16(
                        af[mt], bfr[nt], acc[mt][nt], 0, 0, 0);
            __syncthreads();
        }

        // epilogue: C/D layout col=lane&15, row=(lane>>4)*4+reg  [m89/m91]
        const int col0 = nBase + waveN * 64 + (lane & 15);
        const int row0 = mBase + waveM * 64 + (lane >> 4) * 4;
        #pragma unroll
        for (int mt = 0; mt < 4; mt++) {
            #pragma unroll
            for (int nt = 0; nt < 4; nt++) {
                const int col = col0 + nt * 16;
                const float bv = bias[col];
                #pragma unroll
                for (int r = 0; r < 4; r++) {
                    const int row = row0 + mt * 16 + r;
                    const float z = acc[mt][nt][r] + bv;
                    if (MODE == 1) {
                        float carry = bf2f(A[(size_t)row * K + col]);
                        outB[(size_t)row * NOUT + col] = f2bf(carry + 0.1f * fast_tanh(z));
                    } else if (MODE == 2) {
                        outB[(size_t)row * NOUT + col] = f2bf(fmaxf(z, 0.f));
                    } else {
                        outF[(size_t)row * NOUT + col] = fast_tanh(z);
                    }
                }
            }
        }
    }
}

// ---------------------------------------------------------------------------
// Fused persistent kernel: prep -> gemm1 -> gemm2 -> gemm3 -> gemm4 with
// grid-wide syncs (cooperative launch). LDS: As 8KB + Bs 16KB, Bs doubles as
// the fp32 transpose scratch in prep.
// ---------------------------------------------------------------------------
__global__ __launch_bounds__(512, 4) void fused(
    const float* __restrict__ inp, const float* __restrict__ hz,
    const float* __restrict__ Wf, const float* __restrict__ bff,
    const float* __restrict__ W1, const float* __restrict__ b1,
    const float* __restrict__ W2, const float* __restrict__ b2,
    ushort* __restrict__ bufA, ushort* __restrict__ bufB,
    ushort* __restrict__ WfT, ushort* __restrict__ W1T,
    ushort* __restrict__ W2T, float* __restrict__ out) {
    __shared__ ushort As[128 * 32];   //  8 KB
    __shared__ ushort Bs[256 * 32];   // 16 KB

    cg::grid_group grid = cg::this_grid();
    const int tid = threadIdx.x;
    const int nthr = gridDim.x * 512;

    // ---- phase 0: prep -------------------------------------------------
    // pack h0 = bf16(concat(inp,hz)) : 32768 rows x 256 float4-items/row
    for (int i = blockIdx.x * 512 + tid; i < 32768 * 256; i += nthr) {
        size_t row = (size_t)(i >> 8);
        int col = (i & 255) * 4;
        float4 v = (col < 512) ? *(const float4*)(inp + row * 512 + col)
                               : *(const float4*)(hz + row * 512 + (col - 512));
        ushort4 o = make_ushort4(f2bf(v.x), f2bf(v.y), f2bf(v.z), f2bf(v.w));
        *(ushort4*)(bufA + row * 1024 + col) = o;
    }
    // weight transposes: 2560 32x32 tiles, 2 per block-iteration
    {
        float* tp = (float*)Bs + (tid >> 8) * 1056;  // 32x33 fp32 sub-tile
        const int stid = tid & 255;
        const int tx = stid & 31, ty = stid >> 5;
        for (int t = blockIdx.x; t < 1280; t += gridDim.x) {
            int t2 = t * 2 + (tid >> 8);
            const float* W; ushort* WT; int N = 1024;
            if (t2 < 1024)      { W = Wf; WT = WfT; }
            else if (t2 < 2048) { W = W1; WT = W1T; t2 -= 1024; }
            else                { W = W2; WT = W2T; t2 -= 2048; N = 512; }
            int nb = (t2 % (N / 32)) * 32, kb = (t2 / (N / 32)) * 32;
            #pragma unroll
            for (int j = ty; j < 32; j += 8)
                tp[j * 33 + tx] = W[(size_t)(kb + j) * N + nb + tx];
            __syncthreads();
            #pragma unroll
            for (int j = ty; j < 32; j += 8)
                WT[(size_t)(nb + j) * 1024 + kb + tx] = f2bf(tp[tx * 33 + j]);
            __syncthreads();
        }
    }

    __threadfence(); grid.sync(); __threadfence();
    // ---- phase 1: h1 = h0 + 0.1*tanh(h0@Wf + bf) -----------------------
    gemm_phase<1, 1024, 4>(bufA, WfT, bff, bufB, nullptr, 1024, As, Bs);
    __threadfence(); grid.sync(); __threadfence();
    // ---- phase 2: h2 = h1 + 0.1*tanh(h1@Wf + bf) -----------------------
    gemm_phase<1, 1024, 4>(bufB, WfT, bff, bufA, nullptr, 1024, As, Bs);
    __threadfence(); grid.sync(); __threadfence();
    // ---- phase 3: g = relu(h2@W1 + b1) ---------------------------------
    gemm_phase<2, 1024, 4>(bufA, W1T, b1, bufB, nullptr, 1024, As, Bs);
    __threadfence(); grid.sync(); __threadfence();
    // ---- phase 4: out = tanh(g@W2 + b2) --------------------------------
    gemm_phase<3, 512, 2>(bufB, W2T, b2, nullptr, out, 512, As, Bs);
}

extern "C" void kernel_launch(void* const* d_in, const int* in_sizes, int n_in,
                              void* d_out, int out_size, void* d_ws, size_t ws_size,
                              hipStream_t stream) {
    const float* inp = (const float*)d_in[0];  // [32,1024,512]
    const float* hz  = (const float*)d_in[1];  // [32,1024,512]
    const float* Wf  = (const float*)d_in[2];  // [1024,1024]
    const float* bf_ = (const float*)d_in[3];  // [1024]
    const float* W1  = (const float*)d_in[4];  // [1024,1024]
    const float* b1  = (const float*)d_in[5];  // [1024]
    const float* W2  = (const float*)d_in[6];  // [1024,512]
    const float* b2  = (const float*)d_in[7];  // [512]
    float* out = (float*)d_out;                // [32,1024,512] fp32

    char* ws = (char*)d_ws;
    ushort* WfT  = (ushort*)(ws);                                  // 2 MB
    ushort* W1T  = (ushort*)(ws + (size_t)(2 << 20));              // 2 MB
    ushort* W2T  = (ushort*)(ws + (size_t)(4 << 20));              // 1 MB
    ushort* bufA = (ushort*)(ws + (size_t)(8 << 20));              // 64 MB
    ushort* bufB = (ushort*)(ws + (size_t)(8 << 20) + ((size_t)64 << 20));  // 64 MB

    // co-resident grid size (pure host query — capture-safe, deterministic)
    int maxB = 0;
    if (hipOccupancyMaxActiveBlocksPerMultiprocessor(&maxB, fused, 512, 0) != hipSuccess
        || maxB < 1)
        maxB = 1;
    int nB = maxB * 256;
    if (nB > 1024) nB = 1024;

    void* args[] = {(void*)&inp, (void*)&hz, (void*)&Wf, (void*)&bf_,
                    (void*)&W1, (void*)&b1, (void*)&W2, (void*)&b2,
                    (void*)&bufA, (void*)&bufB, (void*)&WfT, (void*)&W1T,
                    (void*)&W2T, (void*)&out};
    hipLaunchCooperativeKernel((void*)fused, dim3(nB), dim3(512), args, 0, stream);
}

// Round 5
// 1112.837 us; speedup vs baseline: 1.0020x; 1.0020x over previous
//
#include <hip/hip_runtime.h>
#include <hip/hip_bf16.h>
#include <hip/hip_cooperative_groups.h>

namespace cg = cooperative_groups;

typedef __attribute__((ext_vector_type(8))) short short8;
typedef __attribute__((ext_vector_type(4))) float floatx4;

__device__ __forceinline__ ushort f2bf(float x) {
    __hip_bfloat16 h = __float2bfloat16(x);
    return __builtin_bit_cast(ushort, h);
}
__device__ __forceinline__ float bf2f(ushort u) {
    __hip_bfloat16 h = __builtin_bit_cast(__hip_bfloat16, u);
    return __bfloat162float(h);
}

// fast tanh: 1 - 2/(e^{2z}+1); v_exp + v_rcp, ~1e-6 abs err
__device__ __forceinline__ float fast_tanh(float z) {
    float e = __expf(2.0f * z);
    return 1.0f - 2.0f * __builtin_amdgcn_rcpf(e + 1.0f);
}

// async global -> LDS, 16 bytes per lane. LDS dest is wave-uniform base + lane*16;
// per-lane GLOBAL source is arbitrary (exploited for the XOR bank swizzle).
__device__ __forceinline__ void gload_lds16(const ushort* g, ushort* l) {
    __builtin_amdgcn_global_load_lds(
        (const __attribute__((address_space(1))) unsigned int*)(const void*)g,
        (__attribute__((address_space(3))) unsigned int*)(void*)l,
        16, 0, 0);
}

// ---------------------------------------------------------------------------
// One GEMM phase: persistent tile loop over 128(M)x256(N) tiles, 8 waves/block.
// A [M][1024] bf16, BT [NOUT][1024] bf16. Epilogue by MODE:
//   1: out_bf = bf2f(A[row][col]) + 0.1*tanh(acc+bias)   (euler step)
//   2: out_bf = relu(acc+bias)
//   3: out_f32 = tanh(acc+bias)
// Tile id: xcd band = id&7 (grid and strides are multiples of 8, so a block's
// tiles stay in its XCD's A-band); N-tiles innermost for L2 A-reuse.
// ---------------------------------------------------------------------------
template <int MODE, int NOUT, int NX>
__device__ __forceinline__ void gemm_phase(
    const ushort* __restrict__ A, const ushort* __restrict__ BT,
    const float* __restrict__ bias,
    ushort* __restrict__ outB, float* __restrict__ outF,
    int nTiles, ushort* As, ushort* Bs) {
    constexpr int K = 1024;
    const int tid = threadIdx.x;
    const int wave = tid >> 6, lane = tid & 63;
    const int waveM = wave >> 2;      // 0..1  (64-row band)
    const int waveN = wave & 3;       // 0..3  (64-col band)

    // XOR bank swizzle constants: physical 16B slot c holds logical
    // (row r=c>>2, quad q=(c&3)^((r>>1)&3)).
    const int ca = wave * 64 + lane;
    const int ra = ca >> 2;
    const int qa = (ca & 3) ^ ((ra >> 1) & 3);
    ushort* asD  = As + (size_t)(wave * 64) * 8;
    ushort* bsD0 = Bs + (size_t)(wave * 64) * 8;
    ushort* bsD1 = Bs + (size_t)(wave * 64 + 512) * 8;

    const int mrow = lane & 15;
    const int g = lane >> 4;
    const int pq = g ^ ((mrow >> 1) & 3);
    const int kqOff = pq * 8;

    for (int id = blockIdx.x; id < nTiles; id += gridDim.x) {
        const int inner = id >> 3;
        const int nTile = inner % NX;
        const int mTile = (id & 7) * 32 + inner / NX;
        const int mBase = mTile * 128;
        const int nBase = nTile * 256;

        const ushort* agA = A + (size_t)(mBase + ra) * K + qa * 8;
        const ushort* bg0 = BT + (size_t)(nBase + ra) * K + qa * 8;
        const ushort* bg1 = BT + (size_t)(nBase + ra + 128) * K + qa * 8;

        floatx4 acc[4][4];
        #pragma unroll
        for (int i = 0; i < 4; i++)
            #pragma unroll
            for (int j = 0; j < 4; j++) acc[i][j] = (floatx4)(0.f);

        for (int k0 = 0; k0 < K; k0 += 32) {
            gload_lds16(agA + k0, asD);
            gload_lds16(bg0 + k0, bsD0);
            gload_lds16(bg1 + k0, bsD1);
            __syncthreads();

            short8 af[4], bfr[4];
            #pragma unroll
            for (int t = 0; t < 4; t++) {
                af[t]  = *(const short8*)(As + (waveM * 64 + t * 16 + mrow) * 32 + kqOff);
                bfr[t] = *(const short8*)(Bs + (waveN * 64 + t * 16 + mrow) * 32 + kqOff);
            }
            #pragma unroll
            for (int mt = 0; mt < 4; mt++)
                #pragma unroll
                for (int nt = 0; nt < 4; nt++)
                    acc[mt][nt] = __builtin_amdgcn_mfma_f32_16x16x32_bf16(
                        af[mt], bfr[nt], acc[mt][nt], 0, 0, 0);
            __syncthreads();
        }

        // epilogue: C/D layout col=lane&15, row=(lane>>4)*4+reg  [m89/m91]
        const int col0 = nBase + waveN * 64 + (lane & 15);
        const int row0 = mBase + waveM * 64 + (lane >> 4) * 4;
        #pragma unroll
        for (int mt = 0; mt < 4; mt++) {
            #pragma unroll
            for (int nt = 0; nt < 4; nt++) {
                const int col = col0 + nt * 16;
                const float bv = bias[col];
                #pragma unroll
                for (int r = 0; r < 4; r++) {
                    const int row = row0 + mt * 16 + r;
                    const float z = acc[mt][nt][r] + bv;
                    if (MODE == 1) {
                        float carry = bf2f(A[(size_t)row * K + col]);
                        outB[(size_t)row * NOUT + col] = f2bf(carry + 0.1f * fast_tanh(z));
                    } else if (MODE == 2) {
                        outB[(size_t)row * NOUT + col] = f2bf(fmaxf(z, 0.f));
                    } else {
                        outF[(size_t)row * NOUT + col] = fast_tanh(z);
                    }
                }
            }
        }
    }
}

// ---------------------------------------------------------------------------
// Fused persistent kernel: prep -> gemm1 -> gemm2 -> gemm3 -> gemm4 with
// grid-wide syncs (cooperative launch). LDS: As 8KB + Bs 16KB, Bs doubles as
// the fp32 transpose scratch in prep.
// ---------------------------------------------------------------------------
__global__ __launch_bounds__(512, 4) void fused(
    const float* __restrict__ inp, const float* __restrict__ hz,
    const float* __restrict__ Wf, const float* __restrict__ bff,
    const float* __restrict__ W1, const float* __restrict__ b1,
    const float* __restrict__ W2, const float* __restrict__ b2,
    ushort* __restrict__ bufA, ushort* __restrict__ bufB,
    ushort* __restrict__ WfT, ushort* __restrict__ W1T,
    ushort* __restrict__ W2T, float* __restrict__ out) {
    __shared__ ushort As[128 * 32];   //  8 KB
    __shared__ ushort Bs[256 * 32];   // 16 KB

    cg::grid_group grid = cg::this_grid();
    const int tid = threadIdx.x;
    const int nthr = gridDim.x * 512;

    // ---- phase 0: prep -------------------------------------------------
    // pack h0 = bf16(concat(inp,hz)) : 32768 rows x 256 float4-items/row
    for (int i = blockIdx.x * 512 + tid; i < 32768 * 256; i += nthr) {
        size_t row = (size_t)(i >> 8);
        int col = (i & 255) * 4;
        float4 v = (col < 512) ? *(const float4*)(inp + row * 512 + col)
                               : *(const float4*)(hz + row * 512 + (col - 512));
        ushort4 o = make_ushort4(f2bf(v.x), f2bf(v.y), f2bf(v.z), f2bf(v.w));
        *(ushort4*)(bufA + row * 1024 + col) = o;
    }
    // weight transposes: 2560 32x32 tiles, 2 per block-iteration
    {
        float* tp = (float*)Bs + (tid >> 8) * 1056;  // 32x33 fp32 sub-tile
        const int stid = tid & 255;
        const int tx = stid & 31, ty = stid >> 5;
        for (int t = blockIdx.x; t < 1280; t += gridDim.x) {
            int t2 = t * 2 + (tid >> 8);
            const float* W; ushort* WT; int N = 1024;
            if (t2 < 1024)      { W = Wf; WT = WfT; }
            else if (t2 < 2048) { W = W1; WT = W1T; t2 -= 1024; }
            else                { W = W2; WT = W2T; t2 -= 2048; N = 512; }
            int nb = (t2 % (N / 32)) * 32, kb = (t2 / (N / 32)) * 32;
            #pragma unroll
            for (int j = ty; j < 32; j += 8)
                tp[j * 33 + tx] = W[(size_t)(kb + j) * N + nb + tx];
            __syncthreads();
            #pragma unroll
            for (int j = ty; j < 32; j += 8)
                WT[(size_t)(nb + j) * 1024 + kb + tx] = f2bf(tp[tx * 33 + j]);
            __syncthreads();
        }
    }

    __threadfence(); grid.sync(); __threadfence();
    // ---- phase 1: h1 = h0 + 0.1*tanh(h0@Wf + bf) -----------------------
    gemm_phase<1, 1024, 4>(bufA, WfT, bff, bufB, nullptr, 1024, As, Bs);
    __threadfence(); grid.sync(); __threadfence();
    // ---- phase 2: h2 = h1 + 0.1*tanh(h1@Wf + bf) -----------------------
    gemm_phase<1, 1024, 4>(bufB, WfT, bff, bufA, nullptr, 1024, As, Bs);
    __threadfence(); grid.sync(); __threadfence();
    // ---- phase 3: g = relu(h2@W1 + b1) ---------------------------------
    gemm_phase<2, 1024, 4>(bufA, W1T, b1, bufB, nullptr, 1024, As, Bs);
    __threadfence(); grid.sync(); __threadfence();
    // ---- phase 4: out = tanh(g@W2 + b2) --------------------------------
    gemm_phase<3, 512, 2>(bufB, W2T, b2, nullptr, out, 512, As, Bs);
}

extern "C" void kernel_launch(void* const* d_in, const int* in_sizes, int n_in,
                              void* d_out, int out_size, void* d_ws, size_t ws_size,
                              hipStream_t stream) {
    const float* inp = (const float*)d_in[0];  // [32,1024,512]
    const float* hz  = (const float*)d_in[1];  // [32,1024,512]
    const float* Wf  = (const float*)d_in[2];  // [1024,1024]
    const float* bf_ = (const float*)d_in[3];  // [1024]
    const float* W1  = (const float*)d_in[4];  // [1024,1024]
    const float* b1  = (const float*)d_in[5];  // [1024]
    const float* W2  = (const float*)d_in[6];  // [1024,512]
    const float* b2  = (const float*)d_in[7];  // [512]
    float* out = (float*)d_out;                // [32,1024,512] fp32

    char* ws = (char*)d_ws;
    ushort* WfT  = (ushort*)(ws);                                  // 2 MB
    ushort* W1T  = (ushort*)(ws + (size_t)(2 << 20));              // 2 MB
    ushort* W2T  = (ushort*)(ws + (size_t)(4 << 20));              // 1 MB
    ushort* bufA = (ushort*)(ws + (size_t)(8 << 20));              // 64 MB
    ushort* bufB = (ushort*)(ws + (size_t)(8 << 20) + ((size_t)64 << 20));  // 64 MB

    // Cooperative grid MUST be fully co-resident. True footprint is
    // VGPR(60) + AGPR(64) = 124 regs -> 4 waves/SIMD (launch_bounds-guaranteed)
    // -> 2 blocks/CU -> 512 blocks max. The occupancy query sees only arch
    // VGPRs (60) and over-reports (round-4: 1024 blocks -> CWSR preemption
    // thrash at every grid.sync, 457->1115 us). Clamp query to 2/CU.
    int maxB = 0;
    if (hipOccupancyMaxActiveBlocksPerMultiprocessor(&maxB, fused, 512, 0) != hipSuccess
        || maxB < 1)
        maxB = 1;
    if (maxB > 2) maxB = 2;
    int nB = maxB * 256;

    void* args[] = {(void*)&inp, (void*)&hz, (void*)&Wf, (void*)&bf_,
                    (void*)&W1, (void*)&b1, (void*)&W2, (void*)&b2,
                    (void*)&bufA, (void*)&bufB, (void*)&WfT, (void*)&W1T,
                    (void*)&W2T, (void*)&out};
    hipLaunchCooperativeKernel((void*)fused, dim3(nB), dim3(512), args, 0, stream);
}

// Round 6
// 438.164 us; speedup vs baseline: 2.5448x; 2.5398x over previous
//
#include <hip/hip_runtime.h>
#include <hip/hip_bf16.h>

typedef __attribute__((ext_vector_type(8))) short short8;
typedef __attribute__((ext_vector_type(4))) float floatx4;

__device__ __forceinline__ ushort f2bf(float x) {
    __hip_bfloat16 h = __float2bfloat16(x);
    return __builtin_bit_cast(ushort, h);
}
__device__ __forceinline__ float bf2f(ushort u) {
    __hip_bfloat16 h = __builtin_bit_cast(__hip_bfloat16, u);
    return __bfloat162float(h);
}

// fast tanh: 1 - 2/(e^{2z}+1); v_exp + v_rcp, ~1e-6 abs err
__device__ __forceinline__ float fast_tanh(float z) {
    float e = __expf(2.0f * z);
    return 1.0f - 2.0f * __builtin_amdgcn_rcpf(e + 1.0f);
}

// async global -> LDS, 16 bytes per lane. LDS dest is wave-uniform base + lane*16;
// per-lane GLOBAL source is arbitrary (exploited for the XOR bank swizzle).
__device__ __forceinline__ void gload_lds16(const ushort* g, ushort* l) {
    __builtin_amdgcn_global_load_lds(
        (const __attribute__((address_space(1))) unsigned int*)(const void*)g,
        (__attribute__((address_space(3))) unsigned int*)(void*)l,
        16, 0, 0);
}

// ---------------------------------------------------------------------------
// Fused prep (one dispatch): h0 pack + all three weight transposes.
// ---------------------------------------------------------------------------
__global__ void prep(const float* __restrict__ inp, const float* __restrict__ hz,
                     const float* __restrict__ Wf, const float* __restrict__ W1,
                     const float* __restrict__ W2,
                     ushort* __restrict__ h0, ushort* __restrict__ WfT,
                     ushort* __restrict__ W1T, ushort* __restrict__ W2T) {
    int bid = blockIdx.x;
    int tid = threadIdx.x;
    __shared__ float tile[32][33];
    if (bid < 32768) {
        const float* src = (bid < 16384) ? inp : hz;
        int half = (bid < 16384) ? 0 : 1;
        int b = bid - half * 16384;
        size_t i = ((size_t)b * 256 + tid) * 4;   // over 32768*512 floats
        size_t row = i >> 9;
        int col = (int)(i & 511);
        float4 v = *(const float4*)(src + i);
        ushort4 o = make_ushort4(f2bf(v.x), f2bf(v.y), f2bf(v.z), f2bf(v.w));
        *(ushort4*)(h0 + row * 1024 + half * 512 + col) = o;
    } else {
        int t = bid - 32768;
        const float* W;
        ushort* WT;
        int K = 1024, N = 1024;
        if (t < 1024)      { W = Wf; WT = WfT; }
        else if (t < 2048) { W = W1; WT = W1T; t -= 1024; }
        else               { W = W2; WT = W2T; t -= 2048; N = 512; }
        int tx = tid & 31, ty = tid >> 5;
        int nb = (t % (N / 32)) * 32, kb = (t / (N / 32)) * 32;
        #pragma unroll
        for (int j = ty; j < 32; j += 8)
            tile[j][tx] = W[(size_t)(kb + j) * N + nb + tx];
        __syncthreads();
        #pragma unroll
        for (int j = ty; j < 32; j += 8)
            WT[(size_t)(nb + j) * K + kb + tx] = f2bf(tile[tx][j]);
    }
}

// ---------------------------------------------------------------------------
// 128(M)x256(N)-tile bf16 MFMA GEMM, 512 threads / 8 waves, BK=64 (two 32-k
// panels per barrier — halves the vmcnt(0) barrier-drain count vs BK=32).
// A [M][1024] bf16 row-major, BT [NOUT][1024] bf16 (W transposed).
// MODE 1: out_bf = bf2f(A[row][col]) + 0.1*tanh(acc + bias)   (euler step)
// MODE 2: out_bf = relu(acc + bias)
// MODE 3: out_f32 = tanh(acc + bias)
// Grid 1-D: xcd=id&7 owns M-tiles [xcd*32, xcd*32+32); N-tiles innermost.
// ---------------------------------------------------------------------------
template <int MODE, int NOUT, int NX>
__global__ __launch_bounds__(512, 4) void gemm_ep(
    const ushort* __restrict__ A, const ushort* __restrict__ BT,
    const float* __restrict__ bias,
    ushort* __restrict__ outB, float* __restrict__ outF) {
    constexpr int K = 1024;
    __shared__ ushort As[2][128 * 32];   // 16 KB (two 32-k panels)
    __shared__ ushort Bs[2][256 * 32];   // 32 KB

    const int tid = threadIdx.x;
    const int wave = tid >> 6, lane = tid & 63;

    const int id = blockIdx.x;
    const int inner = id >> 3;
    const int nTile = inner % NX;
    const int mTile = (id & 7) * 32 + inner / NX;
    const int mBase = mTile * 128;
    const int nBase = nTile * 256;
    const int waveM = wave >> 2;      // 0..1  (64-row band)
    const int waveN = wave & 3;       // 0..3  (64-col band)

    // Per-panel staging with XOR bank swizzle (identical to the measured
    // zero-conflict BK=32 layout): physical 16B slot c holds logical
    // (row r=c>>2, quad q=(c&3)^((r>>1)&3)). Panel p is a flat +32 k-offset
    // on the same global base and a constant LDS offset — no extra VGPRs.
    const int ca = wave * 64 + lane;
    const int ra = ca >> 2;
    const int qa = (ca & 3) ^ ((ra >> 1) & 3);
    const ushort* agA = A + (size_t)(mBase + ra) * K + qa * 8;
    const ushort* bg0 = BT + (size_t)(nBase + ra) * K + qa * 8;
    const ushort* bg1 = BT + (size_t)(nBase + ra + 128) * K + qa * 8;
    ushort* asD  = &As[0][0] + (size_t)(wave * 64) * 8;
    ushort* bsD0 = &Bs[0][0] + (size_t)(wave * 64) * 8;
    ushort* bsD1 = &Bs[0][0] + (size_t)(wave * 64 + 512) * 8;

    floatx4 acc[4][4];
    #pragma unroll
    for (int i = 0; i < 4; i++)
        #pragma unroll
        for (int j = 0; j < 4; j++) acc[i][j] = (floatx4)(0.f);

    const int mrow = lane & 15;
    const int g = lane >> 4;                  // logical k-quad
    const int pq = g ^ ((mrow >> 1) & 3);     // physical quad
    const int kqOff = pq * 8;

    for (int k0 = 0; k0 < K; k0 += 64) {
        // panel 0 (k0..k0+31) and panel 1 (k0+32..k0+63); one barrier for both
        gload_lds16(agA + k0,      asD);
        gload_lds16(bg0 + k0,      bsD0);
        gload_lds16(bg1 + k0,      bsD1);
        gload_lds16(agA + k0 + 32, asD + 128 * 32);
        gload_lds16(bg0 + k0 + 32, bsD0 + 256 * 32);
        gload_lds16(bg1 + k0 + 32, bsD1 + 256 * 32);
        __syncthreads();

        #pragma unroll
        for (int p = 0; p < 2; p++) {
            short8 af[4], bfr[4];
            #pragma unroll
            for (int t = 0; t < 4; t++) {
                af[t]  = *(const short8*)(&As[p][0] + (waveM * 64 + t * 16 + mrow) * 32 + kqOff);
                bfr[t] = *(const short8*)(&Bs[p][0] + (waveN * 64 + t * 16 + mrow) * 32 + kqOff);
            }
            #pragma unroll
            for (int mt = 0; mt < 4; mt++)
                #pragma unroll
                for (int nt = 0; nt < 4; nt++)
                    acc[mt][nt] = __builtin_amdgcn_mfma_f32_16x16x32_bf16(
                        af[mt], bfr[nt], acc[mt][nt], 0, 0, 0);
        }
        __syncthreads();
    }

    // epilogue: C/D layout col=lane&15, row=(lane>>4)*4+reg  [m89/m91]
    const int col0 = nBase + waveN * 64 + (lane & 15);
    const int row0 = mBase + waveM * 64 + (lane >> 4) * 4;
    #pragma unroll
    for (int mt = 0; mt < 4; mt++) {
        #pragma unroll
        for (int nt = 0; nt < 4; nt++) {
            const int col = col0 + nt * 16;
            const float bv = bias[col];
            #pragma unroll
            for (int r = 0; r < 4; r++) {
                const int row = row0 + mt * 16 + r;
                const float z = acc[mt][nt][r] + bv;
                if (MODE == 1) {
                    float carry = bf2f(A[(size_t)row * K + col]);
                    outB[(size_t)row * NOUT + col] = f2bf(carry + 0.1f * fast_tanh(z));
                } else if (MODE == 2) {
                    outB[(size_t)row * NOUT + col] = f2bf(fmaxf(z, 0.f));
                } else {
                    outF[(size_t)row * NOUT + col] = fast_tanh(z);
                }
            }
        }
    }
}

extern "C" void kernel_launch(void* const* d_in, const int* in_sizes, int n_in,
                              void* d_out, int out_size, void* d_ws, size_t ws_size,
                              hipStream_t stream) {
    const float* inp = (const float*)d_in[0];  // [32,1024,512]
    const float* hz  = (const float*)d_in[1];  // [32,1024,512]
    const float* Wf  = (const float*)d_in[2];  // [1024,1024]
    const float* bf_ = (const float*)d_in[3];  // [1024]
    const float* W1  = (const float*)d_in[4];  // [1024,1024]
    const float* b1  = (const float*)d_in[5];  // [1024]
    const float* W2  = (const float*)d_in[6];  // [1024,512]
    const float* b2  = (const float*)d_in[7];  // [512]
    float* out = (float*)d_out;                // [32,1024,512] fp32

    char* ws = (char*)d_ws;
    ushort* WfT  = (ushort*)(ws);                                  // 2 MB
    ushort* W1T  = (ushort*)(ws + (size_t)(2 << 20));              // 2 MB
    ushort* W2T  = (ushort*)(ws + (size_t)(4 << 20));              // 1 MB
    ushort* bufA = (ushort*)(ws + (size_t)(8 << 20));              // 64 MB
    ushort* bufB = (ushort*)(ws + (size_t)(8 << 20) + ((size_t)64 << 20));  // 64 MB

    // fused prep: h0 pack + 3 weight transposes, one dispatch
    prep<<<35328, 256, 0, stream>>>(inp, hz, Wf, W1, W2, bufA, WfT, W1T, W2T);

    // h1 = h0 + 0.1*tanh(h0@Wf + bf)
    gemm_ep<1, 1024, 4><<<1024, 512, 0, stream>>>(bufA, WfT, bf_, bufB, nullptr);
    // h2 = h1 + 0.1*tanh(h1@Wf + bf)
    gemm_ep<1, 1024, 4><<<1024, 512, 0, stream>>>(bufB, WfT, bf_, bufA, nullptr);
    // g = relu(h2@W1 + b1)
    gemm_ep<2, 1024, 4><<<1024, 512, 0, stream>>>(bufA, W1T, b1, bufB, nullptr);
    // out = tanh(g@W2 + b2)
    gemm_ep<3, 512, 2><<<512, 512, 0, stream>>>(bufB, W2T, b2, nullptr, out);
}